// Round 7
// baseline (325.135 us; speedup 1.0000x reference)
//
#include <hip/hip_runtime.h>

// Conv2d NCHW, stride=1, pad=1, N=16, C=8, K=8, H=W=1024, 3x3, fp32 in/out.
// Round 7: bf16 MFMA implicit GEMM. fp32 VALU path is stuck at ~2x the
// 123us scalar-FMA floor; MFMA moves compute off the critical path entirely.
//   M = 16 w-positions of one h-row, N = 16 co-slots (8 real), K = 72
//   (tap*8+ci) as 3x mfma_f32_16x16x32_bf16; invalid k-slots have ZERO
//   B-fragments so A-garbage there contributes nothing.
// Block: 256 thr, output tile 8h x 124w x 8co. LDS: [row][wl][ci] bf16,
// 16B/wl unit -> ds_write_b128 / ds_read_b128, row padded to 132 units.
// One barrier per block. Weight frags built per-lane from global (L2-hot).
// Edge w-blocks overlap (identical recompute). XCD chunk swizzle for halo L2.

typedef __attribute__((ext_vector_type(8))) short short8;
typedef __attribute__((ext_vector_type(4))) float f32x4;

#define HH 1024
#define WW 1024
#define HW (1024*1024)
#define WB 124          // output cols per block
#define HB 8            // output rows per block
#define SROWS 10        // staged input rows (HB+2)
#define UROW 132        // int4 units per LDS row (128 data + 4 pad)
#define GX 9            // ceil(1024/124)
#define GY 128          // 1024/8
#define GZ 16
#define NBLK (GX*GY*GZ) // 18432 = 8 * 2304

__device__ __forceinline__ unsigned short f2bf(float f) {
    unsigned u = __float_as_uint(f);
    return (unsigned short)((u + 0x7FFFu + ((u >> 16) & 1u)) >> 16);   // RNE
}

__global__ __launch_bounds__(256) void conv3x3_mfma(
    const float* __restrict__ x,      // [16][8][1024][1024]
    const float* __restrict__ wgt,    // [8][8][3][3]
    const float* __restrict__ bias,   // [8]
    float* __restrict__ out)          // [16][8][1024][1024]
{
    __shared__ int4 lds[SROWS * UROW];

    const int tid  = threadIdx.x;
    const int lane = tid & 63;
    const int wv   = tid >> 6;        // wave 0..3
    const int l15  = lane & 15;
    const int ch   = lane >> 4;       // k-chunk / store-row-chunk

    // ---- XCD chunk swizzle: 18432 blocks = 8 XCDs x 2304 contiguous ----
    const unsigned bid  = blockIdx.x;
    const unsigned work = (bid & 7u) * (NBLK / 8u) + (bid >> 3);
    const int wz = (int)(work / (GX * GY));            // n
    const unsigned r1 = work - (unsigned)wz * (GX * GY);
    const int wy = (int)(r1 / GX);                     // h block
    const int wx = (int)(r1 - (unsigned)wy * GX);      // w block

    const int h0 = wy * HB;
    const int w0 = (wx == GX - 1) ? (WW - WB) : wx * WB;   // last block overlaps

    const float* xn = x + (size_t)wz * 8 * HW;

    // ---- per-lane tap -> (kh,kw) LDS offsets (int4 units) ----
    const int t0  = ch;                       // taps 0..3   (MFMA 0)
    const int kh0 = (t0 >= 3) ? 1 : 0;
    const int kw0 = t0 - 3 * kh0;
    const int t1  = 4 + ch;                   // taps 4..7   (MFMA 1)
    const int kh1 = (t1 >= 6) ? 2 : 1;
    const int kw1 = t1 - 3 * kh1;
    const int off0 = kh0 * UROW + kw0;
    const int off1 = kh1 * UROW + kw1;
    const int off2 = 2 * UROW + 2;            // tap 8 (2,2), uniform

    // ---- weight B-fragments: lane l -> col co=l15, k=(ch*8+j) -> tap,ci=j ----
    const int  coc = (l15 < 8) ? l15 : 7;
    const bool com = (l15 < 8);
    short8 b0, b1, b2;
    {
        const float* wp0 = wgt + coc * 72 + kh0 * 3 + kw0;   // + ci*9
        const float* wp1 = wgt + coc * 72 + kh1 * 3 + kw1;
        const float* wp2 = wgt + coc * 72 + 2 * 3 + 2;
#pragma unroll
        for (int j = 0; j < 8; ++j) {
            b0[j] = (short)(com ? f2bf(wp0[j * 9]) : 0);
            b1[j] = (short)(com ? f2bf(wp1[j * 9]) : 0);
            b2[j] = (short)((com && ch == 0) ? f2bf(wp2[j * 9]) : 0);  // taps 9..11 = 0
        }
    }
    const float bv = com ? bias[l15] : 0.0f;

    // ---- stage 10 rows x 128 wl x 8 ci as bf16 (16B per wl) ----
    for (int row = wv; row < SROWS; row += 4) {
        const int gh = h0 - 1 + row;
        if ((unsigned)gh < (unsigned)HH) {
#pragma unroll
            for (int half = 0; half < 2; ++half) {
                const int wl = lane + 64 * half;
                const int gw = w0 - 1 + wl;
                const bool wok = ((unsigned)gw < (unsigned)WW);
                const int gwc = wok ? gw : 0;
                const size_t boff = (size_t)gh * WW + gwc;
                float v[8];
#pragma unroll
                for (int ci = 0; ci < 8; ++ci) {
                    float t = xn[(size_t)ci * HW + boff];
                    v[ci] = wok ? t : 0.0f;
                }
                int4 pk;
                pk.x = (int)f2bf(v[0]) | ((int)f2bf(v[1]) << 16);
                pk.y = (int)f2bf(v[2]) | ((int)f2bf(v[3]) << 16);
                pk.z = (int)f2bf(v[4]) | ((int)f2bf(v[5]) << 16);
                pk.w = (int)f2bf(v[6]) | ((int)f2bf(v[7]) << 16);
                lds[row * UROW + wl] = pk;
            }
        } else {
            int4 z; z.x = z.y = z.z = z.w = 0;
            lds[row * UROW + lane]      = z;   // uniform h-pad row -> zeros
            lds[row * UROW + lane + 64] = z;
        }
    }
    __syncthreads();

    // ---- compute: wave owns h-rows 2wv,2wv+1; 8 w-tiles of 16 each ----
    f32x4 acc[2][8];
#pragma unroll
    for (int th = 0; th < 2; ++th)
#pragma unroll
        for (int wt = 0; wt < 8; ++wt) {
            acc[th][wt].x = bv; acc[th][wt].y = bv;
            acc[th][wt].z = bv; acc[th][wt].w = bv;
        }

#pragma unroll
    for (int th = 0; th < 2; ++th) {
        const int hl = wv * 2 + th;
        const int ub = hl * UROW + l15;       // A row m = l15
#pragma unroll
        for (int wt = 0; wt < 8; ++wt) {
            const int u = ub + wt * 16;
            short8 a0 = *reinterpret_cast<const short8*>(&lds[u + off0]);
            short8 a1 = *reinterpret_cast<const short8*>(&lds[u + off1]);
            short8 a2 = *reinterpret_cast<const short8*>(&lds[u + off2]);
            f32x4 c = acc[th][wt];
            c = __builtin_amdgcn_mfma_f32_16x16x32_bf16(a0, b0, c, 0, 0, 0);
            c = __builtin_amdgcn_mfma_f32_16x16x32_bf16(a1, b1, c, 0, 0, 0);
            c = __builtin_amdgcn_mfma_f32_16x16x32_bf16(a2, b2, c, 0, 0, 0);
            acc[th][wt] = c;
        }
    }

    // ---- store: lane (co=l15<8) holds D rows m=ch*4+r -> float4 along w ----
    if (com) {
#pragma unroll
        for (int th = 0; th < 2; ++th) {
            const int hl = wv * 2 + th;
            float* op = out + ((size_t)wz * 8 + l15) * HW
                            + (size_t)(h0 + hl) * WW + w0;
#pragma unroll
            for (int wt = 0; wt < 8; ++wt) {
                if (wt == 7 && ch == 3) continue;   // w_off 124..127 invalid
                *reinterpret_cast<float4*>(op + wt * 16 + ch * 4) =
                    *reinterpret_cast<const float4*>(&acc[th][wt]);
            }
        }
    }
}

extern "C" void kernel_launch(void* const* d_in, const int* in_sizes, int n_in,
                              void* d_out, int out_size, void* d_ws, size_t ws_size,
                              hipStream_t stream) {
    const float* x    = (const float*)d_in[0];
    const float* wgt  = (const float*)d_in[1];
    const float* bias = (const float*)d_in[2];
    float* out = (float*)d_out;

    dim3 grid(NBLK, 1, 1);
    dim3 block(256, 1, 1);
    conv3x3_mfma<<<grid, block, 0, stream>>>(x, wgt, bias, out);
}